// Round 6
// baseline (37.691 us; speedup 1.0000x reference)
//
#include <hip/hip_runtime.h>
#include <math.h>

// Problem constants: B=16, N=M=4096, K=64.
#define BB 16
#define NN 4096
#define MM 4096
#define CHUNK 2048
#define NCHUNK (MM / CHUNK)
#define ROWS_PER_WAVE 64      // 4 x 16-row A-frags
#define ROWS_PER_BLOCK 256    // 4 waves
#define NCHAMFER (2 * BB * (NN / ROWS_PER_BLOCK))   // 512 blocks

typedef __attribute__((ext_vector_type(8))) short bf16x8;
typedef __attribute__((ext_vector_type(4))) float f32x4;
typedef __attribute__((ext_vector_type(16))) float f32x16;

static __device__ inline unsigned short f2bf(float f) {
    unsigned int u = __float_as_uint(f);
    return (unsigned short)((u + 0x7FFFu + ((u >> 16) & 1u)) >> 16);  // RNE
}
static __device__ inline bf16x8 bzero() {
    bf16x8 z;
    #pragma unroll
    for (int i = 0; i < 8; ++i) z[i] = 0;
    return z;
}
static __device__ inline f32x4 fzero4() {
    f32x4 z; z[0] = z[1] = z[2] = z[3] = 0.f; return z;
}
static __device__ inline f32x16 fzero16() {
    f32x16 z;
    #pragma unroll
    for (int i = 0; i < 16; ++i) z[i] = 0.f;
    return z;
}

// ---------------------------------------------------------------------------
// Mono-kernel, flattened 1D grid of 528 blocks:
//   blocks [0,512): chamfer. d2 complete in one 16x16x32 MFMA:
//     d2 = dot_K5([-2px,-2py,-2pz,p2,1],[tx,ty,tz,1,t2]).
//     f32x4 result tuples keep register pressure ~100 VGPR -> no AGPR copies.
//     Wave owns 64 rows (4 A-frags); block streams all M in 2 LDS chunks.
//   blocks [512,528): regularizer, one wave: G = T.T^T via MFMA, ||G-I||_F.
// ---------------------------------------------------------------------------
__global__ __launch_bounds__(256, 2) void loss_kernel(
    const float* __restrict__ pred, const float* __restrict__ gt,
    const float* __restrict__ trans, float* __restrict__ out)
{
    const int bx  = blockIdx.x;
    const int tid = threadIdx.x;

    if (bx >= NCHAMFER) {
        // ------------------------- regularizer -------------------------
        if (tid < 64) {
            const int b = bx - NCHAMFER;
            const int lane = tid;
            const int hi = lane >> 5, li = lane & 31;
            const float* T = trans + (size_t)b * 64 * 64;
            bf16x8 frag[2][4];
            #pragma unroll
            for (int h = 0; h < 2; ++h)
                #pragma unroll
                for (int s = 0; s < 4; ++s) {
                    const float* rp = T + (size_t)(h * 32 + li) * 64 + s * 16 + hi * 8;
                    const float4 u0 = *(const float4*)rp;
                    const float4 u1 = *(const float4*)(rp + 4);
                    bf16x8 fr;
                    fr[0] = (short)f2bf(u0.x); fr[1] = (short)f2bf(u0.y);
                    fr[2] = (short)f2bf(u0.z); fr[3] = (short)f2bf(u0.w);
                    fr[4] = (short)f2bf(u1.x); fr[5] = (short)f2bf(u1.y);
                    fr[6] = (short)f2bf(u1.z); fr[7] = (short)f2bf(u1.w);
                    frag[h][s] = fr;
                }
            float fsum = 0.f;
            #pragma unroll
            for (int fi = 0; fi < 2; ++fi)
                #pragma unroll
                for (int fj = 0; fj < 2; ++fj) {
                    f32x16 a = fzero16();
                    #pragma unroll
                    for (int s = 0; s < 4; ++s)
                        a = __builtin_amdgcn_mfma_f32_32x32x16_bf16(frag[fi][s], frag[fj][s], a, 0, 0, 0);
                    #pragma unroll
                    for (int r = 0; r < 16; ++r) {
                        const int row = fi * 32 + (r & 3) + 8 * (r >> 2) + 4 * hi;
                        const int col = fj * 32 + li;
                        const float d = a[r] - ((row == col) ? 1.0f : 0.0f);
                        fsum = fmaf(d, d, fsum);
                    }
                }
            #pragma unroll
            for (int off = 32; off > 0; off >>= 1)
                fsum += __shfl_down(fsum, off, 64);
            if (lane == 0)
                atomicAdd(out, (0.1f / (float)BB) * sqrtf(fsum));
        }
        return;
    }

    // --------------------------- chamfer -----------------------------
    __shared__ __align__(16) float smem[8192];   // 32KB stage / 17KB epi (reused)
    __shared__ float ssum[4];

    const int lane = tid & 63;
    const int w    = tid >> 6;
    const int li16 = lane & 15;
    const int g    = lane >> 4;                  // lane group 0..3
    const int dir  = bx & 1;
    const int b    = (bx >> 1) & (BB - 1);
    const int tile = bx >> 5;                    // 0..15
    const float* rows = dir ? gt : pred;
    const float* cols = dir ? pred : gt;
    const float* rb = rows + (size_t)b * NN * 3;
    const float* cball = cols + (size_t)b * MM * 3;

    // A-frags: frag f covers rows rbase + f*16 .. +15. Lane group 0 carries
    // k=0..7 (k0..4 used); groups 1-3 all-zero (their k slots are unused).
    const int rbase = tile * ROWS_PER_BLOCK + w * ROWS_PER_WAVE;
    bf16x8 A[4];
    #pragma unroll
    for (int f = 0; f < 4; ++f) A[f] = bzero();
    if (g == 0) {
        #pragma unroll
        for (int f = 0; f < 4; ++f) {
            const float* rp = rb + (size_t)(rbase + f * 16 + li16) * 3;
            const float px = rp[0], py = rp[1], pz = rp[2];
            const float p2 = px * px + py * py + pz * pz;
            bf16x8 fr = bzero();
            fr[0] = (short)f2bf(-2.f * px);
            fr[1] = (short)f2bf(-2.f * py);
            fr[2] = (short)f2bf(-2.f * pz);
            fr[3] = (short)f2bf(p2);
            fr[4] = (short)0x3F80;          // 1.0
            A[f] = fr;
        }
    }

    float mv[4][4];
    #pragma unroll
    for (int f = 0; f < 4; ++f)
        #pragma unroll
        for (int r = 0; r < 4; ++r) mv[f][r] = 3.4e38f;

    const f32x4 Z = fzero4();
    uint4* sB = (uint4*)smem;
    const bf16x8* sBf = (const bf16x8*)smem;

    for (int ch = 0; ch < NCHUNK; ++ch) {
        if (ch > 0) __syncthreads();             // previous chunk consumed
        const float* cb = cball + (size_t)(ch * CHUNK) * 3;
        #pragma unroll
        for (int i = 0; i < CHUNK / 256; ++i) {
            const int c = i * 256 + tid;
            const float* tp = cb + (size_t)c * 3;
            const float tx = tp[0], ty = tp[1], tz = tp[2];
            const float t2 = tx * tx + ty * ty + tz * tz;
            uint4 pk;
            pk.x = (unsigned)f2bf(tx) | ((unsigned)f2bf(ty) << 16);  // k0,k1
            pk.y = (unsigned)f2bf(tz) | (0x3F80u << 16);             // k2,k3=1.0
            pk.z = (unsigned)f2bf(t2);                               // k4,k5=0
            pk.w = 0u;
            sB[c] = pk;
        }
        __syncthreads();

        // Per jt: 32 cols. All lane groups read the same 16 cols (broadcast);
        // groups 1-3 supply k>=8 which multiplies A's zero slots.
        bf16x8 b1 = sBf[li16], b2 = sBf[16 + li16];
        for (int jt = 0; jt < CHUNK / 32; ++jt) {
            const bf16x8 c1 = b1, c2 = b2;
            if (jt + 1 < CHUNK / 32) {
                b1 = sBf[(jt + 1) * 32 + li16];
                b2 = sBf[(jt + 1) * 32 + 16 + li16];
            }
            f32x4 a1[4], a2[4];
            #pragma unroll
            for (int f = 0; f < 4; ++f) {
                a1[f] = __builtin_amdgcn_mfma_f32_16x16x32_bf16(A[f], c1, Z, 0, 0, 0);
                a2[f] = __builtin_amdgcn_mfma_f32_16x16x32_bf16(A[f], c2, Z, 0, 0, 0);
            }
            #pragma unroll
            for (int f = 0; f < 4; ++f)
                #pragma unroll
                for (int r = 0; r < 4; ++r)
                    mv[f][r] = fminf(fminf(a1[f][r], a2[f][r]), mv[f][r]);  // v_min3
        }
    }

    // Epilogue: C/D map row=(lane>>4)*4+r, col-partial=lane&15.
    // Stash mins [64 rows][16 partials] per wave (stride 17), then one row
    // per lane: reduce 16, sqrt, wave-sum, one atomicAdd per block.
    __syncthreads();
    {
        float* wb = smem + w * 1088;
        #pragma unroll
        for (int f = 0; f < 4; ++f)
            #pragma unroll
            for (int r = 0; r < 4; ++r)
                wb[(f * 16 + g * 4 + r) * 17 + li16] = mv[f][r];
    }
    __syncthreads();

    const float* rr = smem + w * 1088 + lane * 17;
    float m = rr[0];
    #pragma unroll
    for (int c = 1; c < 16; ++c) m = fminf(m, rr[c]);
    float d = sqrtf(fmaxf(m, 0.0f));

    #pragma unroll
    for (int off = 32; off > 0; off >>= 1)
        d += __shfl_down(d, off, 64);
    if (lane == 0) ssum[w] = d;
    __syncthreads();
    if (tid == 0) {
        const float s = ssum[0] + ssum[1] + ssum[2] + ssum[3];
        atomicAdd(out, s * (1.0f / ((float)BB * (float)NN)));
    }
}

extern "C" void kernel_launch(void* const* d_in, const int* in_sizes, int n_in,
                              void* d_out, int out_size, void* d_ws, size_t ws_size,
                              hipStream_t stream)
{
    const float* pred  = (const float*)d_in[0];
    const float* gt    = (const float*)d_in[1];
    const float* trans = (const float*)d_in[2];
    float* out = (float*)d_out;

    hipMemsetAsync(out, 0, sizeof(float), stream);
    loss_kernel<<<dim3(NCHAMFER + BB), dim3(256), 0, stream>>>(pred, gt, trans, out);
}

// Round 7
// 32.919 us; speedup vs baseline: 1.1450x; 1.1450x over previous
//
#include <hip/hip_runtime.h>
#include <math.h>

// Problem constants: B=16, N=M=4096, K=64.
#define BB 16
#define NN 4096
#define MM 4096
#define NSLICE 2
#define SLICE_COLS 2048               // cols staged per block (one shot)
#define NJT (SLICE_COLS / 64)         // 32
#define ROWS_PER_WAVE 128             // 4 x 32-row A-frags
#define ROWS_PER_BLOCK 512            // 4 waves
#define NROWS_TOTAL (2 * BB * NN)     // 131072
#define NCHAMFER 512                  // 8 tiles * 2 slices * 16 b * 2 dir
#define EPW 4352                      // epilogue floats per wave (32*136)

typedef __attribute__((ext_vector_type(8))) short bf16x8;
typedef __attribute__((ext_vector_type(16))) float f32x16;

static __device__ inline unsigned short f2bf(float f) {
    unsigned int u = __float_as_uint(f);
    return (unsigned short)((u + 0x7FFFu + ((u >> 16) & 1u)) >> 16);  // RNE
}
static __device__ inline bf16x8 bzero() {
    bf16x8 z;
    #pragma unroll
    for (int i = 0; i < 8; ++i) z[i] = 0;
    return z;
}
static __device__ inline f32x16 fzero16() {
    f32x16 z;
    #pragma unroll
    for (int i = 0; i < 16; ++i) z[i] = 0.f;
    return z;
}

#define MFMA32(Af, Bf, Cf) __builtin_amdgcn_mfma_f32_32x32x16_bf16(Af, Bf, Cf, 0, 0, 0)
// consume one frag-stage's pair of MFMA results into mv[F] (static F)
#define MINC(F, X1, X2)                                                  \
    do {                                                                 \
        _Pragma("unroll")                                                \
        for (int r = 0; r < 16; ++r)                                     \
            mv[F][r] = fminf(fminf((X1)[r], (X2)[r]), mv[F][r]);         \
    } while (0)

// ---------------------------------------------------------------------------
// Pass A (+reg). d2 complete in-MFMA: d2 = dot_K5([-2p,p2,1],[t,1,t2]).
// Wave = 128 rows (4 A-frags). Block = 512 rows x 2048-col M-slice (LDS).
// jt = 64 cols: 2 ds_read_b128 (prefetched 1 jt ahead), 8 MFMAs issued with
// the min3-consume SKEWED one frag-stage behind (pa/ca ping-pong) so MFMA
// result latency is hidden behind the next frag's issue. Per-slice row-min
// plain-stored to ws. Blocks [512,528): regularizer via MFMA.
// ---------------------------------------------------------------------------
__global__ __launch_bounds__(256, 2) void chamfer_min_kernel(
    const float* __restrict__ pred, const float* __restrict__ gt,
    const float* __restrict__ trans, float* __restrict__ wsmin,
    float* __restrict__ out)
{
    const int bx  = blockIdx.x;
    const int tid = threadIdx.x;

    if (bx >= NCHAMFER) {
        // ------------------------- regularizer -------------------------
        if (tid < 64) {
            const int b = bx - NCHAMFER;
            const int lane = tid;
            const int hi = lane >> 5, li = lane & 31;
            const float* T = trans + (size_t)b * 64 * 64;
            bf16x8 frag[2][4];
            #pragma unroll
            for (int h = 0; h < 2; ++h)
                #pragma unroll
                for (int s = 0; s < 4; ++s) {
                    const float* rp = T + (size_t)(h * 32 + li) * 64 + s * 16 + hi * 8;
                    const float4 u0 = *(const float4*)rp;
                    const float4 u1 = *(const float4*)(rp + 4);
                    bf16x8 fr;
                    fr[0] = (short)f2bf(u0.x); fr[1] = (short)f2bf(u0.y);
                    fr[2] = (short)f2bf(u0.z); fr[3] = (short)f2bf(u0.w);
                    fr[4] = (short)f2bf(u1.x); fr[5] = (short)f2bf(u1.y);
                    fr[6] = (short)f2bf(u1.z); fr[7] = (short)f2bf(u1.w);
                    frag[h][s] = fr;
                }
            float fsum = 0.f;
            #pragma unroll
            for (int fi = 0; fi < 2; ++fi)
                #pragma unroll
                for (int fj = 0; fj < 2; ++fj) {
                    f32x16 a = fzero16();
                    #pragma unroll
                    for (int s = 0; s < 4; ++s)
                        a = MFMA32(frag[fi][s], frag[fj][s], a);
                    #pragma unroll
                    for (int r = 0; r < 16; ++r) {
                        const int row = fi * 32 + (r & 3) + 8 * (r >> 2) + 4 * hi;
                        const int col = fj * 32 + li;
                        const float d = a[r] - ((row == col) ? 1.0f : 0.0f);
                        fsum = fmaf(d, d, fsum);
                    }
                }
            #pragma unroll
            for (int off = 32; off > 0; off >>= 1)
                fsum += __shfl_down(fsum, off, 64);
            if (lane == 0)
                atomicAdd(out, (0.1f / (float)BB) * sqrtf(fsum));
        }
        return;
    }

    // --------------------------- chamfer -----------------------------
    __shared__ __align__(16) float smem[4 * EPW];   // 69.6KB: stage 32KB | epi

    const int lane = tid & 63;
    const int w    = tid >> 6;
    const int li   = lane & 31;
    const int hi   = lane >> 5;
    // bx = tile + 8*(mslice + 2*(b + 16*dir))
    const int tile   = bx & 7;
    const int mslice = (bx >> 3) & 1;
    const int b      = (bx >> 4) & 15;
    const int dir    = bx >> 8;
    const float* rows = dir ? gt : pred;
    const float* cols = dir ? pred : gt;
    const float* rb = rows + (size_t)b * NN * 3;
    const float* cb = cols + ((size_t)b * MM + (size_t)mslice * SLICE_COLS) * 3;

    // A-frags: lanes 0-31 carry k=0..7 (k0..4 used); lanes 32-63 zero.
    const int rbase = tile * ROWS_PER_BLOCK + w * ROWS_PER_WAVE;
    bf16x8 A0 = bzero(), A1 = bzero(), A2 = bzero(), A3 = bzero();
    if (lane < 32) {
        #pragma unroll
        for (int f = 0; f < 4; ++f) {
            const float* rp = rb + (size_t)(rbase + f * 32 + li) * 3;
            const float px = rp[0], py = rp[1], pz = rp[2];
            const float p2 = px * px + py * py + pz * pz;
            bf16x8 fr = bzero();
            fr[0] = (short)f2bf(-2.f * px);
            fr[1] = (short)f2bf(-2.f * py);
            fr[2] = (short)f2bf(-2.f * pz);
            fr[3] = (short)f2bf(p2);
            fr[4] = (short)0x3F80;          // 1.0
            if (f == 0) A0 = fr; else if (f == 1) A1 = fr;
            else if (f == 2) A2 = fr; else A3 = fr;
        }
    }

    // Stage slice: packed bf16x8 per col = (tx,ty,tz,1, t2,0,0,0).
    uint4* sB = (uint4*)smem;
    #pragma unroll
    for (int i = 0; i < SLICE_COLS / 256; ++i) {
        const int c = i * 256 + tid;
        const float* tp = cb + (size_t)c * 3;
        const float tx = tp[0], ty = tp[1], tz = tp[2];
        const float t2 = tx * tx + ty * ty + tz * tz;
        uint4 pk;
        pk.x = (unsigned)f2bf(tx) | ((unsigned)f2bf(ty) << 16);  // k0,k1
        pk.y = (unsigned)f2bf(tz) | (0x3F80u << 16);             // k2,k3=1.0
        pk.z = (unsigned)f2bf(t2);                               // k4,k5=0
        pk.w = 0u;
        sB[c] = pk;
    }
    __syncthreads();

    float mv[4][16];
    #pragma unroll
    for (int f = 0; f < 4; ++f)
        #pragma unroll
        for (int r = 0; r < 16; ++r) mv[f][r] = 3.4e38f;

    const f32x16 Z = fzero16();
    const bf16x8* sBf = (const bf16x8*)smem;

    // Skewed pipeline: issue frag f+1's MFMAs before consuming frag f's.
    bf16x8 c1 = sBf[li], c2 = sBf[32 + li];     // jt=0 cols (lanes>=32 dup)
    bf16x8 b1, b2;
    f32x16 pa1 = MFMA32(A0, c1, Z), pa2 = MFMA32(A0, c2, Z);
    f32x16 ca1, ca2;

    for (int jt = 0; jt < NJT - 1; ++jt) {
        b1 = sBf[(jt + 1) * 64 + li];            // prefetch next jt's cols
        b2 = sBf[(jt + 1) * 64 + 32 + li];
        ca1 = MFMA32(A1, c1, Z); ca2 = MFMA32(A1, c2, Z);
        MINC(0, pa1, pa2);
        pa1 = MFMA32(A2, c1, Z); pa2 = MFMA32(A2, c2, Z);
        MINC(1, ca1, ca2);
        ca1 = MFMA32(A3, c1, Z); ca2 = MFMA32(A3, c2, Z);
        MINC(2, pa1, pa2);
        c1 = b1; c2 = b2;                        // advance cols
        pa1 = MFMA32(A0, c1, Z); pa2 = MFMA32(A0, c2, Z);
        MINC(3, ca1, ca2);
    }
    // last jt (c1,c2 hold final cols)
    ca1 = MFMA32(A1, c1, Z); ca2 = MFMA32(A1, c2, Z);
    MINC(0, pa1, pa2);
    pa1 = MFMA32(A2, c1, Z); pa2 = MFMA32(A2, c2, Z);
    MINC(1, ca1, ca2);
    ca1 = MFMA32(A3, c1, Z); ca2 = MFMA32(A3, c2, Z);
    MINC(2, pa1, pa2);
    MINC(3, ca1, ca2);

    // Epilogue: transpose partial mins via LDS [col li][row 0..127], stride 136.
    // acc mapping: row_local = f*32 + (r&3) + 8*(r>>2) + 4*hi, col = li.
    __syncthreads();
    {
        float* base = smem + w * EPW + li * 136;
        #pragma unroll
        for (int f = 0; f < 4; ++f)
            #pragma unroll
            for (int q = 0; q < 4; ++q) {
                const int rowl = f * 32 + q * 8 + hi * 4;
                *(float4*)&base[rowl] =
                    make_float4(mv[f][4*q], mv[f][4*q+1], mv[f][4*q+2], mv[f][4*q+3]);
            }
    }
    __syncthreads();

    // 512 rows, 256 threads -> rows tid, tid+256; plain stores (unique writer).
    #pragma unroll
    for (int half = 0; half < 2; ++half) {
        const int x = half * 256 + tid;             // 0..511
        const int wsrc = x >> 7;
        const int rl = x & 127;
        const float* rb2 = smem + wsrc * EPW + rl;
        float m = 3.4e38f;
        #pragma unroll
        for (int c = 0; c < 32; ++c) m = fminf(m, rb2[c * 136]);
        wsmin[(size_t)mslice * NROWS_TOTAL + (size_t)(dir * BB + b) * NN
              + tile * ROWS_PER_BLOCK + x] = m;
    }
}

// ---------------------------------------------------------------------------
// Pass B: min over the 2 slices, sqrt, mean-reduce, atomicAdd to out.
// ---------------------------------------------------------------------------
__global__ __launch_bounds__(256) void chamfer_finish_kernel(
    const float* __restrict__ wsmin, float* __restrict__ out)
{
    const int tid = threadIdx.x;
    const int g = blockIdx.x * 256 + tid;           // 0 .. 131071
    const float v = fminf(wsmin[g], wsmin[NROWS_TOTAL + g]);
    float d = sqrtf(fmaxf(v, 0.0f));
    #pragma unroll
    for (int off = 32; off > 0; off >>= 1)
        d += __shfl_down(d, off, 64);
    __shared__ float ssum[4];
    if ((tid & 63) == 0) ssum[tid >> 6] = d;
    __syncthreads();
    if (tid == 0) {
        const float s = ssum[0] + ssum[1] + ssum[2] + ssum[3];
        atomicAdd(out, s * (1.0f / ((float)BB * (float)NN)));
    }
}

extern "C" void kernel_launch(void* const* d_in, const int* in_sizes, int n_in,
                              void* d_out, int out_size, void* d_ws, size_t ws_size,
                              hipStream_t stream)
{
    const float* pred  = (const float*)d_in[0];
    const float* gt    = (const float*)d_in[1];
    const float* trans = (const float*)d_in[2];
    float* out = (float*)d_out;
    float* wsmin = (float*)d_ws;   // 2 * 131072 floats = 1 MB, plain stores

    hipMemsetAsync(out, 0, sizeof(float), stream);
    chamfer_min_kernel<<<dim3(NCHAMFER + BB), dim3(256), 0, stream>>>(
        pred, gt, trans, wsmin, out);
    chamfer_finish_kernel<<<dim3(NROWS_TOTAL / 256), dim3(256), 0, stream>>>(
        wsmin, out);
}